// Round 11
// baseline (89.298 us; speedup 1.0000x reference)
//
#include <hip/hip_runtime.h>
#include <hip/hip_bf16.h>
#include <math.h>

// Problem constants (from reference setup_inputs)
#define BB   8
#define N1   2048
#define N2   2048
#define KK   128
#define TH_  0.1f
#define SL1B 0.1f
#define EPS_ 1e-8f

// Block map (677 blocks, 256 threads each). Chamfer "units" are uniform
// 64-row x 2048-scan blocks (SPLIT=32, SCAN=64, R=8 rows/thread):
//  [0,  256) : pts  -> recon   (b=blk>>5, rowbase=(blk&31)<<6)
//  [256,512) : recon-> pts
//  [512,528) : kpt  -> pts     (b=l>>1, rowbase=(l&1)<<6)
//  [528,544) : pts  -> kpt     full path: 1024 rows/blk, scan=128 broadcast
//  [544,608) : diversity (64 blks x 256 thr x 8 pairs)
//  [608,672) : delta norm (64 blks)
//  [672,676) : NOCS smooth-L1 (4 blks)
//  [676]     : pose
#define NBLOCKS 677

// Chamfer trick: d2(a,b) = |a|^2 + (|b|^2 - 2 a.b). Stage (-2bx,-2by,-2bz,|b|^2)
// in LDS; per pair 3 fma + 0.5 min3; fold |a|^2 after the min (shift-invariant),
// clamp at 0 before sqrt (expansion cancellation guard).
// Tile stride TS=65 f4 (pad +1 per 64-chunk): wave's 8 split-addresses land
// 260*q dwords apart = 4q banks -> the 8 b128 reads cover banks {0-3}..{28-31},
// all 32 banks disjoint: conflict-free.

#define SCAN  64
#define TS    65    // padded tile stride (float4 units)
#define SPLIT 32
#define ROWS  64
#define RPT   8     // rows per thread

__global__ __launch_bounds__(256) void loss_mega_kernel(
        const float* __restrict__ pts,
        const float* __restrict__ rdelta,
        const float* __restrict__ kpt,
        const float* __restrict__ recon,
        const float* __restrict__ pnocs,
        const float* __restrict__ prot,
        const float* __restrict__ ptr_,
        const float* __restrict__ psz,
        const float* __restrict__ rl,
        const float* __restrict__ tl,
        const float* __restrict__ sl,
        float* __restrict__ out) {
    __shared__ float4 tile[SPLIT * TS];    // 2080 f4 = 33.3 KB
    __shared__ float  part[SPLIT * ROWS];  // 2048 f  = 8 KB
    __shared__ float  sbuf[4];

    const int blk = blockIdx.x;
    const int t   = threadIdx.x;
    float v = 0.f;

    if (blk < 528) {
        // ---------- split-path chamfer: 64 rows/blk, R=8, SPLIT=32, SCAN=64 ----------
        const float *Ap, *Bp;
        int NA, rowbase, b;
        float w;
        if (blk < 256) {
            b = blk >> 5; Ap = pts;  NA = N1; Bp = recon;
            rowbase = (blk & 31) << 6; w = 0.5f / 16384.f;
        } else if (blk < 512) {
            int l = blk - 256;
            b = l >> 5; Ap = recon; NA = N2; Bp = pts;
            rowbase = (l & 31) << 6; w = 0.5f / 16384.f;
        } else {
            int l = blk - 512;
            b = l >> 1; Ap = kpt; NA = KK; Bp = pts;
            rowbase = (l & 1) << 6; w = 0.5f / 1024.f;
        }

        // stage all 2048 points of batch b, transformed, padded layout
        #pragma unroll
        for (int i = 0; i < 8; ++i) {
            const int j = t + i * 256;
            const float* p = Bp + ((size_t)b * 2048 + j) * 3;
            float x = p[0], y = p[1], z = p[2];
            tile[j + (j >> 6)] = make_float4(-2.f * x, -2.f * y, -2.f * z,
                                             x * x + y * y + z * z);
        }
        __syncthreads();

        const int g = t & 7;                  // row-group (8 rows each)
        const int q = t >> 3;                 // split index 0..31
        float ax[RPT], ay[RPT], az[RPT], asq[RPT], m[RPT];
        #pragma unroll
        for (int k = 0; k < RPT; ++k) {
            const float* pa = Ap + ((size_t)b * NA + rowbase + g * RPT + k) * 3;
            ax[k] = pa[0]; ay[k] = pa[1]; az[k] = pa[2];
            asq[k] = ax[k] * ax[k] + ay[k] * ay[k] + az[k] * az[k];
            m[k] = 3.4e38f;
        }

        const int off = q * TS;
        #pragma unroll 4
        for (int j = 0; j < SCAN; j += 2) {
            float4 q0 = tile[off + j];        // 8 addrs/wave, disjoint banks
            float4 q1 = tile[off + j + 1];
            #pragma unroll
            for (int k = 0; k < RPT; ++k) {
                float e0 = fmaf(ax[k], q0.x,
                           fmaf(ay[k], q0.y,
                           fmaf(az[k], q0.z, q0.w)));
                float e1 = fmaf(ax[k], q1.x,
                           fmaf(ay[k], q1.y,
                           fmaf(az[k], q1.z, q1.w)));
                m[k] = fminf(fminf(m[k], e0), e1);   // v_min3_f32
            }
        }
        #pragma unroll
        for (int k = 0; k < RPT; ++k)
            part[q * ROWS + g * RPT + k] = asq[k] + m[k];
        __syncthreads();
        if (t < ROWS) {
            float mm = part[t];
            #pragma unroll
            for (int qq = 1; qq < SPLIT; qq += 2)
                mm = fminf(fminf(mm, part[qq * ROWS + t]),
                           part[(qq + 1 < SPLIT ? qq + 1 : qq) * ROWS + t]);
            v = sqrtf(fmaxf(mm, 0.f)) * w;
        }
    } else if (blk < 544) {
        // ---------- full-path chamfer: pts -> kpt, 1024 rows/blk, R=4, broadcast ----------
        const int l = blk - 528;
        const int b = l >> 1;
        const int rowbase = (l & 1) << 10;
        const float w = 0.5f / 16384.f;

        for (int j = t; j < KK; j += 256) {
            const float* p = kpt + ((size_t)b * KK + j) * 3;
            float x = p[0], y = p[1], z = p[2];
            tile[j] = make_float4(-2.f * x, -2.f * y, -2.f * z,
                                  x * x + y * y + z * z);
        }
        __syncthreads();

        float ax[4], ay[4], az[4], asq[4], m[4];
        #pragma unroll
        for (int k = 0; k < 4; ++k) {
            const float* pa = pts + ((size_t)b * N1 + rowbase + t * 4 + k) * 3;
            ax[k] = pa[0]; ay[k] = pa[1]; az[k] = pa[2];
            asq[k] = ax[k] * ax[k] + ay[k] * ay[k] + az[k] * az[k];
            m[k] = 3.4e38f;
        }
        #pragma unroll 4
        for (int j = 0; j < KK; j += 2) {
            float4 q0 = tile[j];              // pure broadcast
            float4 q1 = tile[j + 1];
            #pragma unroll
            for (int k = 0; k < 4; ++k) {
                float e0 = fmaf(ax[k], q0.x,
                           fmaf(ay[k], q0.y,
                           fmaf(az[k], q0.z, q0.w)));
                float e1 = fmaf(ax[k], q1.x,
                           fmaf(ay[k], q1.y,
                           fmaf(az[k], q1.z, q1.w)));
                m[k] = fminf(fminf(m[k], e0), e1);
            }
        }
        float s = 0.f;
        #pragma unroll
        for (int k = 0; k < 4; ++k)
            s += sqrtf(fmaxf(asq[k] + m[k], 0.f));
        v = s * w;
    } else if (blk < 608) {
        // ---------- diversity: 64 blocks x 256 thr x 8 pairs ----------
        const int local = blk - 544;
        float acc = 0.f;
        #pragma unroll
        for (int u = 0; u < 8; ++u) {
            const int gg = local * 2048 + u * 256 + t;   // [0, 131072)
            const int b = gg >> 14, i = (gg >> 7) & 127, j = gg & 127;
            const float* pi = kpt + ((size_t)((b << 7) + i)) * 3;
            const float* pj = kpt + ((size_t)((b << 7) + j)) * 3;
            float dx = pi[0] - pj[0], dy = pi[1] - pj[1], dz = pi[2] - pj[2];
            float d2 = dx * dx + dy * dy + dz * dz;
            acc += (i == j) ? TH_ : fminf(sqrtf(d2), TH_);
        }
        v = acc * (1.0f / 131072.0f);
    } else if (blk < 672) {
        // ---------- delta magnitude ----------
        const int gg = (blk - 608) * 256 + t;            // [0, 16384)
        const float* p = rdelta + (size_t)gg * 3;
        v = sqrtf(p[0] * p[0] + p[1] * p[1] + p[2] * p[2]) * (1.0f / 16384.0f);
    } else if (blk < 676) {
        // ---------- NOCS smooth-L1 ----------
        const int gg = (blk - 672) * 256 + t;            // [0, 1024)
        const int b = gg >> 7, k = gg & 127;
        const float* s3 = sl + b * 3;
        float scale = sqrtf(s3[0] * s3[0] + s3[1] * s3[1] + s3[2] * s3[2]) + EPS_;
        const float* t3 = tl + b * 3;
        const float* p3 = kpt + ((size_t)((b << 7) + k)) * 3;
        float p0 = (p3[0] - t3[0]) / scale;
        float p1 = (p3[1] - t3[1]) / scale;
        float p2 = (p3[2] - t3[2]) / scale;
        const float* R = rl + b * 9;
        const float* pn = pnocs + ((size_t)((b << 7) + k)) * 3;
        float s = 0.f;
        #pragma unroll
        for (int j = 0; j < 3; ++j) {
            float gt = p0 * R[j] + p1 * R[3 + j] + p2 * R[6 + j];
            float diff = fabsf(pn[j] - gt);
            s += (diff > SL1B) ? (diff - 0.5f * SL1B) : (diff * diff * (0.5f / SL1B));
        }
        v = s * (1.0f / 1024.0f);
    } else {
        // ---------- pose ----------
        if (t < BB) {
            const int b = t;
            float s = 0.f;
            #pragma unroll
            for (int j = 0; j < 3; ++j) {
                float c = 0.f;
                #pragma unroll
                for (int i = 0; i < 3; ++i) {
                    float d = prot[b * 9 + i * 3 + j] - rl[b * 9 + i * 3 + j];
                    c += d * d;
                }
                s += sqrtf(c);
            }
            v = s * (1.0f / 24.0f);
            float dt2 = 0.f, ds2 = 0.f;
            #pragma unroll
            for (int i = 0; i < 3; ++i) {
                float dt = ptr_[b * 3 + i] - tl[b * 3 + i]; dt2 += dt * dt;
                float ds = psz[b * 3 + i] - sl[b * 3 + i]; ds2 += ds * ds;
            }
            v += (sqrtf(dt2) + sqrtf(ds2)) * (1.0f / 8.0f);
        }
    }

    // block reduction + single atomicAdd (uniform control flow per block)
    #pragma unroll
    for (int off = 32; off > 0; off >>= 1)
        v += __shfl_down(v, off, 64);
    if ((t & 63) == 0) sbuf[t >> 6] = v;
    __syncthreads();
    if (t == 0) atomicAdd(out, sbuf[0] + sbuf[1] + sbuf[2] + sbuf[3]);
}

extern "C" void kernel_launch(void* const* d_in, const int* in_sizes, int n_in,
                              void* d_out, int out_size, void* d_ws, size_t ws_size,
                              hipStream_t stream) {
    const float* pts    = (const float*)d_in[0];
    const float* rdelta = (const float*)d_in[1];
    const float* kpt    = (const float*)d_in[2];
    const float* recon  = (const float*)d_in[3];
    const float* pnocs  = (const float*)d_in[4];
    const float* prot   = (const float*)d_in[5];
    const float* ptr_   = (const float*)d_in[6];
    const float* psz    = (const float*)d_in[7];
    const float* rl     = (const float*)d_in[8];
    const float* tl     = (const float*)d_in[9];
    const float* sl     = (const float*)d_in[10];
    float* out = (float*)d_out;

    // d_out poisoned 0xAA before every call — zero it (stream op, capturable)
    hipMemsetAsync(d_out, 0, sizeof(float), stream);

    loss_mega_kernel<<<NBLOCKS, 256, 0, stream>>>(
        pts, rdelta, kpt, recon, pnocs, prot, ptr_, psz, rl, tl, sl, out);
}

// Round 15
// 82.230 us; speedup vs baseline: 1.0860x; 1.0860x over previous
//
#include <hip/hip_runtime.h>
#include <hip/hip_bf16.h>
#include <math.h>

// Problem constants (from reference setup_inputs)
#define BB   8
#define N1   2048
#define N2   2048
#define KK   128
#define TH_  0.1f
#define SL1B 0.1f
#define EPS_ 1e-8f

// Block map (677 blocks, 256 threads each). Chamfer "units" are uniform
// 64-row x 2048-scan blocks (SPLIT=32, SCAN=64, R=8 rows/thread):
//  [0,  256) : pts  -> recon   (b=blk>>5, rowbase=(blk&31)<<6)
//  [256,512) : recon-> pts
//  [512,528) : kpt  -> pts     (b=l>>1, rowbase=(l&1)<<6)
//  [528,544) : pts  -> kpt     full path: 1024 rows/blk, scan=128 broadcast
//  [544,608) : diversity (64 blks x 256 thr x 8 pairs)
//  [608,672) : delta norm (64 blks)
//  [672,676) : NOCS smooth-L1 (4 blks)
//  [676]     : pose
// Epilogue: per-block partial -> plain store ws[blk] (NO atomics, poison-safe);
// final_reduce kernel (1 block) sums 677 partials -> out[0] (no memset node).
#define NBLOCKS 677

// Chamfer trick: d2(a,b) = |a|^2 + (|b|^2 - 2 a.b). Stage (-2bx,-2by,-2bz,|b|^2)
// in LDS; per pair 3 fma + 0.5 min3; fold |a|^2 after the min (shift-invariant),
// clamp at 0 before sqrt (expansion cancellation guard).
// Tile stride TS=65 f4 (pad +1 per 64-chunk): wave's 8 split-addresses land
// 260*q dwords apart = 4q banks -> the 8 b128 reads cover banks {0-3}..{28-31},
// all 32 banks disjoint: conflict-free.

#define SCAN  64
#define TS    65    // padded tile stride (float4 units)
#define SPLIT 32
#define ROWS  64
#define RPT   8     // rows per thread

__global__ __launch_bounds__(256) void loss_mega_kernel(
        const float* __restrict__ pts,
        const float* __restrict__ rdelta,
        const float* __restrict__ kpt,
        const float* __restrict__ recon,
        const float* __restrict__ pnocs,
        const float* __restrict__ prot,
        const float* __restrict__ ptr_,
        const float* __restrict__ psz,
        const float* __restrict__ rl,
        const float* __restrict__ tl,
        const float* __restrict__ sl,
        float* __restrict__ ws) {
    __shared__ float4 tile[SPLIT * TS];    // 2080 f4 = 33.3 KB
    __shared__ float  part[SPLIT * ROWS];  // 2048 f  = 8 KB
    __shared__ float  sbuf[4];

    const int blk = blockIdx.x;
    const int t   = threadIdx.x;
    float v = 0.f;

    if (blk < 528) {
        // ---------- split-path chamfer: 64 rows/blk, R=8, SPLIT=32, SCAN=64 ----------
        const float *Ap, *Bp;
        int NA, rowbase, b;
        float w;
        if (blk < 256) {
            b = blk >> 5; Ap = pts;  NA = N1; Bp = recon;
            rowbase = (blk & 31) << 6; w = 0.5f / 16384.f;
        } else if (blk < 512) {
            int l = blk - 256;
            b = l >> 5; Ap = recon; NA = N2; Bp = pts;
            rowbase = (l & 31) << 6; w = 0.5f / 16384.f;
        } else {
            int l = blk - 512;
            b = l >> 1; Ap = kpt; NA = KK; Bp = pts;
            rowbase = (l & 1) << 6; w = 0.5f / 1024.f;
        }

        // stage all 2048 points of batch b, transformed, padded layout
        #pragma unroll
        for (int i = 0; i < 8; ++i) {
            const int j = t + i * 256;
            const float* p = Bp + ((size_t)b * 2048 + j) * 3;
            float x = p[0], y = p[1], z = p[2];
            tile[j + (j >> 6)] = make_float4(-2.f * x, -2.f * y, -2.f * z,
                                             x * x + y * y + z * z);
        }
        __syncthreads();

        const int g = t & 7;                  // row-group (8 rows each)
        const int q = t >> 3;                 // split index 0..31
        float ax[RPT], ay[RPT], az[RPT], asq[RPT], m[RPT];
        #pragma unroll
        for (int k = 0; k < RPT; ++k) {
            const float* pa = Ap + ((size_t)b * NA + rowbase + g * RPT + k) * 3;
            ax[k] = pa[0]; ay[k] = pa[1]; az[k] = pa[2];
            asq[k] = ax[k] * ax[k] + ay[k] * ay[k] + az[k] * az[k];
            m[k] = 3.4e38f;
        }

        const int off = q * TS;
        #pragma unroll 4
        for (int j = 0; j < SCAN; j += 2) {
            float4 q0 = tile[off + j];        // 8 addrs/wave, disjoint banks
            float4 q1 = tile[off + j + 1];
            #pragma unroll
            for (int k = 0; k < RPT; ++k) {
                float e0 = fmaf(ax[k], q0.x,
                           fmaf(ay[k], q0.y,
                           fmaf(az[k], q0.z, q0.w)));
                float e1 = fmaf(ax[k], q1.x,
                           fmaf(ay[k], q1.y,
                           fmaf(az[k], q1.z, q1.w)));
                m[k] = fminf(fminf(m[k], e0), e1);   // v_min3_f32
            }
        }
        #pragma unroll
        for (int k = 0; k < RPT; ++k)
            part[q * ROWS + g * RPT + k] = asq[k] + m[k];
        __syncthreads();
        if (t < ROWS) {
            float mm = part[t];
            #pragma unroll
            for (int qq = 1; qq < SPLIT; qq += 2)
                mm = fminf(fminf(mm, part[qq * ROWS + t]),
                           part[(qq + 1 < SPLIT ? qq + 1 : qq) * ROWS + t]);
            v = sqrtf(fmaxf(mm, 0.f)) * w;
        }
    } else if (blk < 544) {
        // ---------- full-path chamfer: pts -> kpt, 1024 rows/blk, R=4, broadcast ----------
        const int l = blk - 528;
        const int b = l >> 1;
        const int rowbase = (l & 1) << 10;
        const float w = 0.5f / 16384.f;

        for (int j = t; j < KK; j += 256) {
            const float* p = kpt + ((size_t)b * KK + j) * 3;
            float x = p[0], y = p[1], z = p[2];
            tile[j] = make_float4(-2.f * x, -2.f * y, -2.f * z,
                                  x * x + y * y + z * z);
        }
        __syncthreads();

        float ax[4], ay[4], az[4], asq[4], m[4];
        #pragma unroll
        for (int k = 0; k < 4; ++k) {
            const float* pa = pts + ((size_t)b * N1 + rowbase + t * 4 + k) * 3;
            ax[k] = pa[0]; ay[k] = pa[1]; az[k] = pa[2];
            asq[k] = ax[k] * ax[k] + ay[k] * ay[k] + az[k] * az[k];
            m[k] = 3.4e38f;
        }
        #pragma unroll 4
        for (int j = 0; j < KK; j += 2) {
            float4 q0 = tile[j];              // pure broadcast
            float4 q1 = tile[j + 1];
            #pragma unroll
            for (int k = 0; k < 4; ++k) {
                float e0 = fmaf(ax[k], q0.x,
                           fmaf(ay[k], q0.y,
                           fmaf(az[k], q0.z, q0.w)));
                float e1 = fmaf(ax[k], q1.x,
                           fmaf(ay[k], q1.y,
                           fmaf(az[k], q1.z, q1.w)));
                m[k] = fminf(fminf(m[k], e0), e1);
            }
        }
        float s = 0.f;
        #pragma unroll
        for (int k = 0; k < 4; ++k)
            s += sqrtf(fmaxf(asq[k] + m[k], 0.f));
        v = s * w;
    } else if (blk < 608) {
        // ---------- diversity: 64 blocks x 256 thr x 8 pairs ----------
        const int local = blk - 544;
        float acc = 0.f;
        #pragma unroll
        for (int u = 0; u < 8; ++u) {
            const int gg = local * 2048 + u * 256 + t;   // [0, 131072)
            const int b = gg >> 14, i = (gg >> 7) & 127, j = gg & 127;
            const float* pi = kpt + ((size_t)((b << 7) + i)) * 3;
            const float* pj = kpt + ((size_t)((b << 7) + j)) * 3;
            float dx = pi[0] - pj[0], dy = pi[1] - pj[1], dz = pi[2] - pj[2];
            float d2 = dx * dx + dy * dy + dz * dz;
            acc += (i == j) ? TH_ : fminf(sqrtf(d2), TH_);
        }
        v = acc * (1.0f / 131072.0f);
    } else if (blk < 672) {
        // ---------- delta magnitude ----------
        const int gg = (blk - 608) * 256 + t;            // [0, 16384)
        const float* p = rdelta + (size_t)gg * 3;
        v = sqrtf(p[0] * p[0] + p[1] * p[1] + p[2] * p[2]) * (1.0f / 16384.0f);
    } else if (blk < 676) {
        // ---------- NOCS smooth-L1 ----------
        const int gg = (blk - 672) * 256 + t;            // [0, 1024)
        const int b = gg >> 7, k = gg & 127;
        const float* s3 = sl + b * 3;
        float scale = sqrtf(s3[0] * s3[0] + s3[1] * s3[1] + s3[2] * s3[2]) + EPS_;
        const float* t3 = tl + b * 3;
        const float* p3 = kpt + ((size_t)((b << 7) + k)) * 3;
        float p0 = (p3[0] - t3[0]) / scale;
        float p1 = (p3[1] - t3[1]) / scale;
        float p2 = (p3[2] - t3[2]) / scale;
        const float* R = rl + b * 9;
        const float* pn = pnocs + ((size_t)((b << 7) + k)) * 3;
        float s = 0.f;
        #pragma unroll
        for (int j = 0; j < 3; ++j) {
            float gt = p0 * R[j] + p1 * R[3 + j] + p2 * R[6 + j];
            float diff = fabsf(pn[j] - gt);
            s += (diff > SL1B) ? (diff - 0.5f * SL1B) : (diff * diff * (0.5f / SL1B));
        }
        v = s * (1.0f / 1024.0f);
    } else {
        // ---------- pose ----------
        if (t < BB) {
            const int b = t;
            float s = 0.f;
            #pragma unroll
            for (int j = 0; j < 3; ++j) {
                float c = 0.f;
                #pragma unroll
                for (int i = 0; i < 3; ++i) {
                    float d = prot[b * 9 + i * 3 + j] - rl[b * 9 + i * 3 + j];
                    c += d * d;
                }
                s += sqrtf(c);
            }
            v = s * (1.0f / 24.0f);
            float dt2 = 0.f, ds2 = 0.f;
            #pragma unroll
            for (int i = 0; i < 3; ++i) {
                float dt = ptr_[b * 3 + i] - tl[b * 3 + i]; dt2 += dt * dt;
                float ds = psz[b * 3 + i] - sl[b * 3 + i]; ds2 += ds * ds;
            }
            v += (sqrtf(dt2) + sqrtf(ds2)) * (1.0f / 8.0f);
        }
    }

    // block reduction + ONE plain store per block (no atomics, no d_out init)
    #pragma unroll
    for (int off = 32; off > 0; off >>= 1)
        v += __shfl_down(v, off, 64);
    if ((t & 63) == 0) sbuf[t >> 6] = v;
    __syncthreads();
    if (t == 0) ws[blk] = sbuf[0] + sbuf[1] + sbuf[2] + sbuf[3];
}

__global__ __launch_bounds__(256) void final_reduce(const float* __restrict__ ws,
                                                    float* __restrict__ out) {
    __shared__ float sbuf[4];
    const int t = threadIdx.x;
    float v = 0.f;
    #pragma unroll
    for (int i = t; i < NBLOCKS; i += 256) v += ws[i];
    #pragma unroll
    for (int off = 32; off > 0; off >>= 1)
        v += __shfl_down(v, off, 64);
    if ((t & 63) == 0) sbuf[t >> 6] = v;
    __syncthreads();
    if (t == 0) out[0] = sbuf[0] + sbuf[1] + sbuf[2] + sbuf[3];
}

extern "C" void kernel_launch(void* const* d_in, const int* in_sizes, int n_in,
                              void* d_out, int out_size, void* d_ws, size_t ws_size,
                              hipStream_t stream) {
    const float* pts    = (const float*)d_in[0];
    const float* rdelta = (const float*)d_in[1];
    const float* kpt    = (const float*)d_in[2];
    const float* recon  = (const float*)d_in[3];
    const float* pnocs  = (const float*)d_in[4];
    const float* prot   = (const float*)d_in[5];
    const float* ptr_   = (const float*)d_in[6];
    const float* psz    = (const float*)d_in[7];
    const float* rl     = (const float*)d_in[8];
    const float* tl     = (const float*)d_in[9];
    const float* sl     = (const float*)d_in[10];
    float* out = (float*)d_out;
    float* ws  = (float*)d_ws;

    // No memset needed: ws[0..676] fully overwritten by mega kernel (plain
    // stores), out[0] fully overwritten by final_reduce.
    loss_mega_kernel<<<NBLOCKS, 256, 0, stream>>>(
        pts, rdelta, kpt, recon, pnocs, prot, ptr_, psz, rl, tl, sl, ws);
    final_reduce<<<1, 256, 0, stream>>>(ws, out);
}